// Round 20
// baseline (73.211 us; speedup 1.0000x reference)
//
#include <hip/hip_runtime.h>
#include <cstdint>

#define NB 32
#define NL 512
#define NE 256
#define NH 8
#define ND 64
#define NM 16384   // NB*NL
#define NHD 512    // NH*ND

using half8  = __attribute__((ext_vector_type(8))) _Float16;
using half4  = __attribute__((ext_vector_type(4))) _Float16;
using f32x4  = __attribute__((ext_vector_type(4))) float;
using f32x16 = __attribute__((ext_vector_type(16))) float;
using u32x2  = __attribute__((ext_vector_type(2))) unsigned int;

__device__ __forceinline__ f32x4 mfma16(half8 a, half8 b, f32x4 c) {
    return __builtin_amdgcn_mfma_f32_16x16x32_f16(a, b, c, 0, 0, 0);
}
__device__ __forceinline__ f32x16 mfma32(half8 a, half8 b, f32x16 c) {
    return __builtin_amdgcn_mfma_f32_32x32x16_f16(a, b, c, 0, 0, 0);
}
// async global->LDS, 16B/lane; LDS dest = wave-uniform base + lane*16.
__device__ __forceinline__ void cp16_g2l(const void* g, void* l) {
    __builtin_amdgcn_global_load_lds(
        (const __attribute__((address_space(1))) void*)g,
        (__attribute__((address_space(3))) void*)l, 16, 0, 0);
}
// 2^x on the TRANS pipe (v_exp_f32), no libm dependence.
__device__ __forceinline__ float exp2fast(float x) {
    return __builtin_amdgcn_exp2f(x);
}
// fast tanh: ~6 ops, 2 on TRANS pipe. |err| ~1e-6, invisible under f16.
__device__ __forceinline__ float fast_tanh(float x) {
    float xc = fminf(fmaxf(x, -9.f), 9.f);
    float t = exp2fast(xc * 2.88539008178f);   // e^(2x) = 2^(2x*log2e)
    return (t - 1.f) * __builtin_amdgcn_rcpf(t + 1.f);
}
// pack two f32 -> two f16 in one u32 (v_cvt_pkrtz_f16_f32)
__device__ __forceinline__ uint32_t pk16(float a, float b) {
    auto h2 = __builtin_amdgcn_cvt_pkrtz(a, b);
    return __builtin_bit_cast(uint32_t, h2);
}

// ---------------- K0: fused weight repack + xph = f16(x+pos) ----------------
__global__ __launch_bounds__(256) void prep(
        const float* __restrict__ x, const float* __restrict__ pos,
        const float* __restrict__ Wq, const float* __restrict__ Wk,
        const float* __restrict__ Wv, const float* __restrict__ Wo,
        _Float16* __restrict__ wqkv, _Float16* __restrict__ woh,
        _Float16* __restrict__ xph) {
    int bid = blockIdx.x;
    if (bid < 2048) {
        int idx = bid * 256 + threadIdx.x;
        if (idx < 1536 * 256) {
            int n = idx >> 8, e = idx & 255;
            int s = n >> 9, h = (n >> 6) & 7, d = n & 63;
            const float* W = (s == 0) ? Wq : (s == 1) ? Wk : Wv;
            wqkv[idx] = (_Float16)W[(h * NE + e) * ND + d];
        } else {
            int j = idx - 1536 * 256;
            int e = j >> 9, f = j & 511;
            woh[j] = (_Float16)Wo[f * NE + e];
        }
    } else {
        int i = ((bid - 2048) * 256 + threadIdx.x) * 4;
        float4 xv = *(const float4*)(x + i);
        float4 pv = *(const float4*)(pos + (i & (NL * NE - 1)));
        half4 o;
        o[0] = (_Float16)(xv.x + pv.x);
        o[1] = (_Float16)(xv.y + pv.y);
        o[2] = (_Float16)(xv.z + pv.z);
        o[3] = (_Float16)(xv.w + pv.w);
        *(half4*)(xph + i) = o;
    }
}

// ---------------- K1: fully-fused QKV projection + flash attention ----------
// One block per (b,h); 512 threads (8 waves); K/V panels resident in LDS.
// Phase A: Q/K/V = tanh(xph @ W) via 16 staged sub-GEMMs (unchanged, verified).
// Phase B: TWO SEQUENTIAL q-passes (qs outer, kt inner, per-pass epilogue):
//   persistent regs drop 96->64 (acc_o of one stream + both qf), softmax+PV
//   fused per-ks (verified R17 math) -> ~15-20 free VGPRs of scheduling
//   headroom. Fixed-base softmax (|s|<8 from tanh bounds) -- exact math.
// Grid: 256 = 8 XCD x 32, b-major per XCD (xph panel L2-local).
__global__ __launch_bounds__(512, 2) void attn_fused(
        const _Float16* __restrict__ wqkv, const _Float16* __restrict__ xph,
        _Float16* __restrict__ attn_out) {
    __shared__ _Float16 Kp[512 * 64];    // [key][d], u^=(key&7); alias: staging
    __shared__ _Float16 Vtp[64 * 512];   // [d][key], u^=(d&7);  alias: Q scratch
    _Float16* Xs = Kp;                   // staging X [128][64]  (16 KB)
    _Float16* Ws = Kp + 128 * 64;        // staging W 3x[64][64] (24 KB)
    _Float16* Qs = Vtp;                  // Q panel scratch [512][64]

    int tid = threadIdx.x;
    int w8 = tid >> 6, l = tid & 63;
    int l31 = l & 31, hi = l >> 5;
    int rt = w8 & 3, d2w = w8 >> 2;
    int g0 = ((blockIdx.x & 7) << 5) + (blockIdx.x >> 3);
    int h = g0 & 7, b = g0 >> 3;
    const float C1 = 0.125f * 1.44269504089f;   // scale * log2(e)
    const float C4 = 4.f * 1.44269504089f;      // fixed softmax base m=4

    int lrow8 = l >> 3;
    int kc16 = (l & 7) ^ lrow8;          // pre-swizzled global 16B k-unit
    const _Float16* xg = xph + (size_t)(b * NL) * 256;
    const _Float16* wg = wqkv + (size_t)(h * 64) * 256;  // Q rows; +512/1024*256 for K/V

    // ---- Phase A: projections. wave role: rows rt*32 (+r*128), d-half d2w.
    f32x16 acc_q[4] = {}, acc_k[4] = {}, acc_v[4] = {};
    for (int kt2 = 0; kt2 < 4; ++kt2) {
#pragma unroll
        for (int r = 0; r < 4; ++r) {
#pragma unroll
            for (int i = 0; i < 2; ++i) {          // X rows r*128..+127, 64-k slice
                int c = w8 * 2 + i;
                int row = c * 8 + lrow8;
                cp16_g2l(xg + (size_t)(r * 128 + row) * 256 + kt2 * 64 + kc16 * 8,
                         Xs + c * 512);
            }
            if (r == 0) {                           // W q/k/v, 64-k slice
                int row = w8 * 8 + lrow8;
#pragma unroll
                for (int s = 0; s < 3; ++s)
                    cp16_g2l(wg + (size_t)s * 512 * 256 + (size_t)row * 256 + kt2 * 64 + kc16 * 8,
                             Ws + s * 4096 + w8 * 512);
            }
            __syncthreads();
#pragma unroll
            for (int ks2 = 0; ks2 < 4; ++ks2) {
                int rowb = rt * 32 + l31;
                half8 bf = *(const half8*)(Xs + rowb * 64 + (((ks2 * 2 + hi) ^ (rowb & 7)) << 3));
                int rowa = d2w * 32 + l31;
                int sa = rowa * 64 + (((ks2 * 2 + hi) ^ (rowa & 7)) << 3);
                half8 aq = *(const half8*)(Ws + sa);
                half8 ak = *(const half8*)(Ws + 4096 + sa);
                half8 av = *(const half8*)(Ws + 8192 + sa);
                acc_q[r] = mfma32(aq, bf, acc_q[r]);    // lane=q,   regs=d
                acc_k[r] = mfma32(ak, bf, acc_k[r]);    // lane=key, regs=d
                acc_v[r] = mfma32(bf, av, acc_v[r]);    // lane=d,   regs=key
            }
            __syncthreads();
        }
    }

    // ---- pack + tanh -> Qs (Vtp area) and Kp (staging done, safe) ----
#pragma unroll
    for (int r = 0; r < 4; ++r) {
        uint32_t cq[4][2], ck[4][2];
#pragma unroll
        for (int a = 0; a < 4; ++a)
#pragma unroll
            for (int p = 0; p < 2; ++p) {
                cq[a][p] = pk16(fast_tanh(acc_q[r][4 * a + 2 * p]),
                                fast_tanh(acc_q[r][4 * a + 2 * p + 1]));
                ck[a][p] = pk16(fast_tanh(acc_k[r][4 * a + 2 * p]),
                                fast_tanh(acc_k[r][4 * a + 2 * p + 1]));
            }
        int rowq = r * 128 + rt * 32 + l31;      // q or key row
#pragma unroll
        for (int ks = 0; ks < 2; ++ks) {
            u32x2 q0 = __builtin_amdgcn_permlane32_swap(cq[2 * ks][0], cq[2 * ks + 1][0], false, false);
            u32x2 q1 = __builtin_amdgcn_permlane32_swap(cq[2 * ks][1], cq[2 * ks + 1][1], false, false);
            u32x2 k0 = __builtin_amdgcn_permlane32_swap(ck[2 * ks][0], ck[2 * ks + 1][0], false, false);
            u32x2 k1 = __builtin_amdgcn_permlane32_swap(ck[2 * ks][1], ck[2 * ks + 1][1], false, false);
            union { uint32_t u[4]; half8 h8; } pq, pk;
            pq.u[0] = q0[0]; pq.u[1] = q1[0]; pq.u[2] = q0[1]; pq.u[3] = q1[1];
            pk.u[0] = k0[0]; pk.u[1] = k1[0]; pk.u[2] = k0[1]; pk.u[3] = k1[1];
            int uu = d2w * 4 + ks * 2 + hi;      // d-unit
            *(half8*)(Qs + rowq * 64 + ((uu ^ (rowq & 7)) << 3)) = pq.h8;
            *(half8*)(Kp + rowq * 64 + ((uu ^ (rowq & 7)) << 3)) = pk.h8;
        }
    }
    __syncthreads();
    // reload qf in attention assignment: wave w8 owns q rows w8*64..+63
    half8 qf[2][4];
#pragma unroll
    for (int qs = 0; qs < 2; ++qs)
#pragma unroll
        for (int ks = 0; ks < 4; ++ks) {
            int q = w8 * 64 + qs * 32 + l31;
            qf[qs][ks] = *(const half8*)(Qs + q * 64 + (((ks * 2 + hi) ^ (q & 7)) << 3));
        }
    __syncthreads();
    // ---- write Vtp (overwrites Qs) ----
#pragma unroll
    for (int r = 0; r < 4; ++r) {
        uint32_t cv[4][2];
#pragma unroll
        for (int a = 0; a < 4; ++a)
#pragma unroll
            for (int p = 0; p < 2; ++p)
                cv[a][p] = pk16(fast_tanh(acc_v[r][4 * a + 2 * p]),
                                fast_tanh(acc_v[r][4 * a + 2 * p + 1]));
        int d = d2w * 32 + l31;
#pragma unroll
        for (int ks = 0; ks < 2; ++ks) {
            u32x2 v0 = __builtin_amdgcn_permlane32_swap(cv[2 * ks][0], cv[2 * ks + 1][0], false, false);
            u32x2 v1 = __builtin_amdgcn_permlane32_swap(cv[2 * ks][1], cv[2 * ks + 1][1], false, false);
            union { uint32_t u[4]; half8 h8; } pv;
            pv.u[0] = v0[0]; pv.u[1] = v1[0]; pv.u[2] = v0[1]; pv.u[3] = v1[1];
            int uu = r * 16 + rt * 4 + ks * 2 + hi;   // key-unit (0..63)
            *(half8*)(Vtp + d * 512 + ((uu ^ (d & 7)) << 3)) = pv.h8;
        }
    }
    __syncthreads();

    // ---- Phase B: two sequential q-passes; per-ks fused softmax+PV ----
#pragma unroll
    for (int qs = 0; qs < 2; ++qs) {
        f32x16 acc_o[2] = {};
        float lrow = 0.f;
        for (int kt = 0; kt < 8; ++kt) {
            f32x16 acc_s[2] = {};
            __builtin_amdgcn_s_setprio(1);
#pragma unroll
            for (int ks = 0; ks < 4; ++ks)
#pragma unroll
                for (int kb2 = 0; kb2 < 2; ++kb2) {
                    int key = kt * 64 + kb2 * 32 + l31;
                    half8 kb = *(const half8*)(Kp + key * 64 + (((ks * 2 + hi) ^ (key & 7)) << 3));
                    acc_s[kb2] = mfma32(kb, qf[qs][ks], acc_s[kb2]);
                }
            __builtin_amdgcn_s_setprio(0);
            // p = 2^(s*C1 - C4) = e^(s/8 - 4); |s/8| < 8 always (tanh bounds).
            float rs = 0.f;
#pragma unroll
            for (int ks = 0; ks < 4; ++ks) {
                int kb2 = ks >> 1, s = ks & 1;
                float p0 = exp2fast(fmaf(acc_s[kb2][8 * s + 0], C1, -C4));
                float p1 = exp2fast(fmaf(acc_s[kb2][8 * s + 1], C1, -C4));
                float p2 = exp2fast(fmaf(acc_s[kb2][8 * s + 2], C1, -C4));
                float p3 = exp2fast(fmaf(acc_s[kb2][8 * s + 3], C1, -C4));
                float p4 = exp2fast(fmaf(acc_s[kb2][8 * s + 4], C1, -C4));
                float p5 = exp2fast(fmaf(acc_s[kb2][8 * s + 5], C1, -C4));
                float p6 = exp2fast(fmaf(acc_s[kb2][8 * s + 6], C1, -C4));
                float p7 = exp2fast(fmaf(acc_s[kb2][8 * s + 7], C1, -C4));
                rs += ((p0 + p1) + (p2 + p3)) + ((p4 + p5) + (p6 + p7));
                uint32_t we0 = pk16(p0, p1), we1 = pk16(p2, p3);
                uint32_t wo0 = pk16(p4, p5), wo1 = pk16(p6, p7);
                u32x2 r0 = __builtin_amdgcn_permlane32_swap(we0, wo0, false, false);
                u32x2 r1 = __builtin_amdgcn_permlane32_swap(we1, wo1, false, false);
                union { uint32_t u[4]; half8 h8; } pu;
                pu.u[0] = r0[0]; pu.u[1] = r1[0]; pu.u[2] = r0[1]; pu.u[3] = r1[1];
                __builtin_amdgcn_s_setprio(1);
#pragma unroll
                for (int d2 = 0; d2 < 2; ++d2) {
                    int d = d2 * 32 + l31;
                    int uu = kt * 8 + ks * 2 + hi;
                    half8 vb = *(const half8*)(Vtp + d * 512 + ((uu ^ (d & 7)) << 3));
                    acc_o[d2] = mfma32(pu.h8, vb, acc_o[d2]);
                }
                __builtin_amdgcn_s_setprio(0);
            }
            lrow += rs;
        }
        // per-pass epilogue: acc_o dies here -> frees registers for next pass
        lrow += __shfl_xor(lrow, 32);
        size_t orow0 = (size_t)(b * NL + w8 * 64 + qs * 32);
#pragma unroll
        for (int c = 0; c < 4; ++c)
#pragma unroll
            for (int r = 0; r < 4; ++r) {
                int qrow = c * 8 + hi * 4 + r;
                float inv = 1.f / __shfl(lrow, qrow);
#pragma unroll
                for (int d2 = 0; d2 < 2; ++d2)
                    attn_out[(orow0 + qrow) * NHD + h * ND + d2 * 32 + l31] =
                        (_Float16)(acc_o[d2][c * 4 + r] * inv);
            }
    }
}

// ---------------- K2: output projection + f16 tanh residual ----------------
// tile 128e x 64m. BK=64, swizzled dbuf LDS, 2-phase pipeline.
// Grid: 512 = 8 XCD x (2 tn x 32 tm) -> attn B-panel fetched once per XCD.
__global__ __launch_bounds__(256) void final_gemm(
        const _Float16* __restrict__ woh, const _Float16* __restrict__ attn,
        const _Float16* __restrict__ xph, float* __restrict__ out) {
    __shared__ _Float16 Alds[2][128 * 64];
    __shared__ _Float16 Blds[2][64 * 64];
    int tid = threadIdx.x;
    int w = tid >> 6, l = tid & 63;
    int bid = blockIdx.x;
    int xcd = bid & 7, local = bid >> 3;   // 0..63
    int tn = local & 1;
    int tm = xcd * 32 + (local >> 1);
    int wn = w >> 1, wm = w & 1;
    int m16 = l & 15, g = l >> 4;
    int lrow8 = l >> 3;
    int kc16 = (l & 7) ^ lrow8;
    f32x4 acc[4][2] = {};

    const _Float16* Ag = woh + (size_t)tn * 128 * 512;
    const _Float16* Bg = attn + (size_t)tm * 64 * 512;

#define FIN_STAGE(kt, buf)                                                    \
    _Pragma("unroll") for (int i = 0; i < 4; ++i) {                           \
        int cA = w * 4 + i;                                                   \
        int row = cA * 8 + lrow8;                                             \
        cp16_g2l(Ag + (size_t)row * 512 + (kt) * 64 + kc16 * 8,               \
                 &Alds[buf][cA * 512]);                                       \
    }                                                                         \
    _Pragma("unroll") for (int i = 0; i < 2; ++i) {                           \
        int cB = w * 2 + i;                                                   \
        int row = cB * 8 + lrow8;                                             \
        cp16_g2l(Bg + (size_t)row * 512 + (kt) * 64 + kc16 * 8,               \
                 &Blds[buf][cB * 512]);                                       \
    }

    FIN_STAGE(0, 0);
    __syncthreads();
    int cur = 0;
    for (int kt = 0; kt < 8; ++kt) {
        if (kt < 7) { FIN_STAGE(kt + 1, cur ^ 1); }
#pragma unroll
        for (int ks = 0; ks < 2; ++ks) {
            half8 af[4], bf[2];
#pragma unroll
            for (int f = 0; f < 4; ++f) {
                int ra = wn * 64 + f * 16 + m16;
                af[f] = *(const half8*)(&Alds[cur][ra * 64 + (((ks * 4 + g) ^ (ra & 7)) << 3)]);
            }
#pragma unroll
            for (int f = 0; f < 2; ++f) {
                int rb = wm * 32 + f * 16 + m16;
                bf[f] = *(const half8*)(&Blds[cur][rb * 64 + (((ks * 4 + g) ^ (rb & 7)) << 3)]);
            }
#pragma unroll
            for (int nf = 0; nf < 4; ++nf)
#pragma unroll
                for (int mf = 0; mf < 2; ++mf)
                    acc[nf][mf] = mfma16(af[nf], bf[mf], acc[nf][mf]);
        }
        __syncthreads();
        cur ^= 1;
    }
#undef FIN_STAGE
#pragma unroll
    for (int nf = 0; nf < 4; ++nf) {
        int e = tn * 128 + wn * 64 + nf * 16 + g * 4;
#pragma unroll
        for (int mf = 0; mf < 2; ++mf) {
            int m = tm * 64 + wm * 32 + mf * 16 + m16;
            half4 hx = *(const half4*)(xph + (size_t)m * NE + e);
            f32x4 v = acc[nf][mf];
            float4 o;
            o.x = v[0] + fast_tanh((float)hx[0]);
            o.y = v[1] + fast_tanh((float)hx[1]);
            o.z = v[2] + fast_tanh((float)hx[2]);
            o.w = v[3] + fast_tanh((float)hx[3]);
            *(float4*)(out + (size_t)m * NE + e) = o;
        }
    }
}

extern "C" void kernel_launch(void* const* d_in, const int* in_sizes, int n_in,
                              void* d_out, int out_size, void* d_ws, size_t ws_size,
                              hipStream_t stream) {
    const float* x   = (const float*)d_in[0];
    const float* pos = (const float*)d_in[1];
    const float* Wq  = (const float*)d_in[2];
    const float* Wk  = (const float*)d_in[3];
    const float* Wv  = (const float*)d_in[4];
    const float* Wo  = (const float*)d_in[5];
    float* out = (float*)d_out;

    char* ws = (char*)d_ws;
    _Float16* xph   = (_Float16*)(ws);              //  8,388,608 B
    _Float16* wqkv  = (_Float16*)(ws + 8388608);    //    786,432 B
    _Float16* woh   = (_Float16*)(ws + 9175040);    //    262,144 B
    _Float16* attn  = (_Float16*)(ws + 9437184);    // 16,777,216 B

    prep<<<dim3(6144), dim3(256), 0, stream>>>(x, pos, Wq, Wk, Wv, Wo, wqkv, woh, xph);
    attn_fused<<<dim3(256), dim3(512), 0, stream>>>(wqkv, xph, attn);
    final_gemm<<<dim3(512), dim3(256), 0, stream>>>(woh, attn, xph, out);
}

// Round 21
// 69.734 us; speedup vs baseline: 1.0499x; 1.0499x over previous
//
#include <hip/hip_runtime.h>
#include <cstdint>

#define NB 32
#define NL 512
#define NE 256
#define NH 8
#define ND 64
#define NM 16384   // NB*NL
#define NHD 512    // NH*ND

using half8  = __attribute__((ext_vector_type(8))) _Float16;
using half4  = __attribute__((ext_vector_type(4))) _Float16;
using f32x4  = __attribute__((ext_vector_type(4))) float;
using f32x16 = __attribute__((ext_vector_type(16))) float;
using u32x2  = __attribute__((ext_vector_type(2))) unsigned int;

__device__ __forceinline__ f32x4 mfma16(half8 a, half8 b, f32x4 c) {
    return __builtin_amdgcn_mfma_f32_16x16x32_f16(a, b, c, 0, 0, 0);
}
__device__ __forceinline__ f32x16 mfma32(half8 a, half8 b, f32x16 c) {
    return __builtin_amdgcn_mfma_f32_32x32x16_f16(a, b, c, 0, 0, 0);
}
// async global->LDS, 16B/lane; LDS dest = wave-uniform base + lane*16.
__device__ __forceinline__ void cp16_g2l(const void* g, void* l) {
    __builtin_amdgcn_global_load_lds(
        (const __attribute__((address_space(1))) void*)g,
        (__attribute__((address_space(3))) void*)l, 16, 0, 0);
}
// 2^x on the TRANS pipe (v_exp_f32), no libm dependence.
__device__ __forceinline__ float exp2fast(float x) {
    return __builtin_amdgcn_exp2f(x);
}
// fast tanh: ~6 ops, 2 on TRANS pipe. |err| ~1e-6, invisible under f16.
__device__ __forceinline__ float fast_tanh(float x) {
    float xc = fminf(fmaxf(x, -9.f), 9.f);
    float t = exp2fast(xc * 2.88539008178f);   // e^(2x) = 2^(2x*log2e)
    return (t - 1.f) * __builtin_amdgcn_rcpf(t + 1.f);
}
// pack two f32 -> two f16 in one u32 (v_cvt_pkrtz_f16_f32)
__device__ __forceinline__ uint32_t pk16(float a, float b) {
    auto h2 = __builtin_amdgcn_cvt_pkrtz(a, b);
    return __builtin_bit_cast(uint32_t, h2);
}

// ---------------- K0: fused weight repack + xph = f16(x+pos) ----------------
__global__ __launch_bounds__(256) void prep(
        const float* __restrict__ x, const float* __restrict__ pos,
        const float* __restrict__ Wq, const float* __restrict__ Wk,
        const float* __restrict__ Wv, const float* __restrict__ Wo,
        _Float16* __restrict__ wqkv, _Float16* __restrict__ woh,
        _Float16* __restrict__ xph) {
    int bid = blockIdx.x;
    if (bid < 2048) {
        int idx = bid * 256 + threadIdx.x;
        if (idx < 1536 * 256) {
            int n = idx >> 8, e = idx & 255;
            int s = n >> 9, h = (n >> 6) & 7, d = n & 63;
            const float* W = (s == 0) ? Wq : (s == 1) ? Wk : Wv;
            wqkv[idx] = (_Float16)W[(h * NE + e) * ND + d];
        } else {
            int j = idx - 1536 * 256;
            int e = j >> 9, f = j & 511;
            woh[j] = (_Float16)Wo[f * NE + e];
        }
    } else {
        int i = ((bid - 2048) * 256 + threadIdx.x) * 4;
        float4 xv = *(const float4*)(x + i);
        float4 pv = *(const float4*)(pos + (i & (NL * NE - 1)));
        half4 o;
        o[0] = (_Float16)(xv.x + pv.x);
        o[1] = (_Float16)(xv.y + pv.y);
        o[2] = (_Float16)(xv.z + pv.z);
        o[3] = (_Float16)(xv.w + pv.w);
        *(half4*)(xph + i) = o;
    }
}

// ---------------- K1: fully-fused QKV projection + flash attention ----------
// One block per (b,h); 512 threads (8 waves); K/V panels resident in LDS.
// Phase A: Q/K/V = tanh(xph @ W), T4-pipelined staging: X double-buffered,
//   counted s_waitcnt vmcnt(2) (prefetch stays in flight a full stage),
//   raw s_barrier (no drain), W prefetched at kt2 boundaries.
// Phase B: interleaved 2-q-stream attention, fixed-base softmax (|s|<8 from
//   tanh bounds -- exact math, no online max).
// Grid: 256 = 8 XCD x 32, b-major per XCD (xph panel L2-local).
__global__ __launch_bounds__(512, 2) void attn_fused(
        const _Float16* __restrict__ wqkv, const _Float16* __restrict__ xph,
        _Float16* __restrict__ attn_out) {
    __shared__ _Float16 Kp[512 * 64];    // [key][d], u^=(key&7); alias: staging
    __shared__ _Float16 Vtp[64 * 512];   // [d][key], u^=(d&7);  alias: Q scratch
    // staging layout inside Kp (Phase A only): X dbuf 2x16KB, W 24KB @ +32KB
    _Float16* Ws = Kp + 16384;           // 3x[64][64] = 24 KB (ends at 56 KB)
    _Float16* Qs = Vtp;                  // Q panel scratch [512][64]

    int tid = threadIdx.x;
    int w8 = tid >> 6, l = tid & 63;
    int l31 = l & 31, hi = l >> 5;
    int rt = w8 & 3, d2w = w8 >> 2;
    int g0 = ((blockIdx.x & 7) << 5) + (blockIdx.x >> 3);
    int h = g0 & 7, b = g0 >> 3;
    const float C1 = 0.125f * 1.44269504089f;   // scale * log2(e)
    const float C4 = 4.f * 1.44269504089f;      // fixed softmax base m=4

    int lrow8 = l >> 3;
    int kc16 = (l & 7) ^ lrow8;          // pre-swizzled global 16B k-unit
    const _Float16* xg = xph + (size_t)(b * NL) * 256;
    const _Float16* wg = wqkv + (size_t)(h * 64) * 256;  // Q rows; +512/1024*256 for K/V

    // ---- Phase A: pipelined projections ----
    f32x16 acc_q[4] = {}, acc_k[4] = {}, acc_v[4] = {};

#define ISSUE_X(kt2_, r_, buf_)                                               \
    _Pragma("unroll") for (int i = 0; i < 2; ++i) {                           \
        int c = w8 * 2 + i;                                                   \
        int row = c * 8 + lrow8;                                              \
        cp16_g2l(xg + (size_t)((r_) * 128 + row) * 256 + (kt2_) * 64 + kc16 * 8, \
                 Kp + (buf_) * 8192 + c * 512);                               \
    }
#define ISSUE_W(kt2_)                                                         \
    {                                                                         \
        int row = w8 * 8 + lrow8;                                             \
        _Pragma("unroll") for (int s = 0; s < 3; ++s)                         \
            cp16_g2l(wg + (size_t)s * 512 * 256 + (size_t)row * 256 + (kt2_) * 64 + kc16 * 8, \
                     Ws + s * 4096 + w8 * 512);                               \
    }
#define PA_MFMA(buf_, r_)                                                     \
    _Pragma("unroll") for (int ks2 = 0; ks2 < 4; ++ks2) {                     \
        int rowb = rt * 32 + l31;                                             \
        half8 bf = *(const half8*)(Kp + (buf_) * 8192 + rowb * 64 +           \
                                   (((ks2 * 2 + hi) ^ (rowb & 7)) << 3));     \
        int rowa = d2w * 32 + l31;                                            \
        int sa = rowa * 64 + (((ks2 * 2 + hi) ^ (rowa & 7)) << 3);            \
        half8 aq = *(const half8*)(Ws + sa);                                  \
        half8 ak = *(const half8*)(Ws + 4096 + sa);                           \
        half8 av = *(const half8*)(Ws + 8192 + sa);                           \
        acc_q[r_] = mfma32(aq, bf, acc_q[r_]);                                \
        acc_k[r_] = mfma32(ak, bf, acc_k[r_]);                                \
        acc_v[r_] = mfma32(bf, av, acc_v[r_]);                                \
    }

    ISSUE_X(0, 0, 0);
    ISSUE_W(0);
    asm volatile("s_waitcnt vmcnt(0)" ::: "memory");
    __builtin_amdgcn_s_barrier();
    __builtin_amdgcn_sched_barrier(0);
#pragma unroll
    for (int it = 0; it < 16; ++it) {
        int kt2 = it >> 2, r = it & 3, buf = it & 1;
        if (it < 15) {
            int nx = it + 1;
            ISSUE_X(nx >> 2, nx & 3, buf ^ 1);   // prefetch next X slice
            asm volatile("s_waitcnt vmcnt(2)" ::: "memory");  // X(it) done
        } else {
            asm volatile("s_waitcnt vmcnt(0)" ::: "memory");
        }
        __builtin_amdgcn_s_barrier();            // X(it) visible to all
        __builtin_amdgcn_sched_barrier(0);
        PA_MFMA(buf, r);
        if (it < 15) {
            __builtin_amdgcn_sched_barrier(0);
            __builtin_amdgcn_s_barrier();        // all reads of buf/Ws done
            if (r == 3) ISSUE_W(kt2 + 1);        // safe: readers finished
        }
    }
    __syncthreads();                             // full drain before pack
#undef ISSUE_X
#undef ISSUE_W
#undef PA_MFMA

    // ---- pack + tanh -> Qs (Vtp area) and Kp (staging done, safe) ----
#pragma unroll
    for (int r = 0; r < 4; ++r) {
        uint32_t cq[4][2], ck[4][2];
#pragma unroll
        for (int a = 0; a < 4; ++a)
#pragma unroll
            for (int p = 0; p < 2; ++p) {
                cq[a][p] = pk16(fast_tanh(acc_q[r][4 * a + 2 * p]),
                                fast_tanh(acc_q[r][4 * a + 2 * p + 1]));
                ck[a][p] = pk16(fast_tanh(acc_k[r][4 * a + 2 * p]),
                                fast_tanh(acc_k[r][4 * a + 2 * p + 1]));
            }
        int rowq = r * 128 + rt * 32 + l31;      // q or key row
#pragma unroll
        for (int ks = 0; ks < 2; ++ks) {
            u32x2 q0 = __builtin_amdgcn_permlane32_swap(cq[2 * ks][0], cq[2 * ks + 1][0], false, false);
            u32x2 q1 = __builtin_amdgcn_permlane32_swap(cq[2 * ks][1], cq[2 * ks + 1][1], false, false);
            u32x2 k0 = __builtin_amdgcn_permlane32_swap(ck[2 * ks][0], ck[2 * ks + 1][0], false, false);
            u32x2 k1 = __builtin_amdgcn_permlane32_swap(ck[2 * ks][1], ck[2 * ks + 1][1], false, false);
            union { uint32_t u[4]; half8 h8; } pq, pk;
            pq.u[0] = q0[0]; pq.u[1] = q1[0]; pq.u[2] = q0[1]; pq.u[3] = q1[1];
            pk.u[0] = k0[0]; pk.u[1] = k1[0]; pk.u[2] = k0[1]; pk.u[3] = k1[1];
            int uu = d2w * 4 + ks * 2 + hi;      // d-unit
            *(half8*)(Qs + rowq * 64 + ((uu ^ (rowq & 7)) << 3)) = pq.h8;
            *(half8*)(Kp + rowq * 64 + ((uu ^ (rowq & 7)) << 3)) = pk.h8;
        }
    }
    __syncthreads();
    // reload qf in attention assignment: wave w8 owns q rows w8*64..+63
    half8 qf[2][4];
#pragma unroll
    for (int qs = 0; qs < 2; ++qs)
#pragma unroll
        for (int ks = 0; ks < 4; ++ks) {
            int q = w8 * 64 + qs * 32 + l31;
            qf[qs][ks] = *(const half8*)(Qs + q * 64 + (((ks * 2 + hi) ^ (q & 7)) << 3));
        }
    __syncthreads();
    // ---- write Vtp (overwrites Qs) ----
#pragma unroll
    for (int r = 0; r < 4; ++r) {
        uint32_t cv[4][2];
#pragma unroll
        for (int a = 0; a < 4; ++a)
#pragma unroll
            for (int p = 0; p < 2; ++p)
                cv[a][p] = pk16(fast_tanh(acc_v[r][4 * a + 2 * p]),
                                fast_tanh(acc_v[r][4 * a + 2 * p + 1]));
        int d = d2w * 32 + l31;
#pragma unroll
        for (int ks = 0; ks < 2; ++ks) {
            u32x2 v0 = __builtin_amdgcn_permlane32_swap(cv[2 * ks][0], cv[2 * ks + 1][0], false, false);
            u32x2 v1 = __builtin_amdgcn_permlane32_swap(cv[2 * ks][1], cv[2 * ks + 1][1], false, false);
            union { uint32_t u[4]; half8 h8; } pv;
            pv.u[0] = v0[0]; pv.u[1] = v1[0]; pv.u[2] = v0[1]; pv.u[3] = v1[1];
            int uu = r * 16 + rt * 4 + ks * 2 + hi;   // key-unit (0..63)
            *(half8*)(Vtp + d * 512 + ((uu ^ (d & 7)) << 3)) = pv.h8;
        }
    }
    __syncthreads();

    // ---- Phase B: attention, fixed-base softmax (no max tracking) ----
    f32x16 acc_o[2][2] = {};
    float lrow[2] = {0.f, 0.f};
    for (int kt = 0; kt < 8; ++kt) {
#pragma unroll
        for (int qs = 0; qs < 2; ++qs) {
            f32x16 acc_s[2] = {};
            __builtin_amdgcn_s_setprio(1);
#pragma unroll
            for (int ks = 0; ks < 4; ++ks)
#pragma unroll
                for (int kb2 = 0; kb2 < 2; ++kb2) {
                    int key = kt * 64 + kb2 * 32 + l31;
                    half8 kb = *(const half8*)(Kp + key * 64 + (((ks * 2 + hi) ^ (key & 7)) << 3));
                    acc_s[kb2] = mfma32(kb, qf[qs][ks], acc_s[kb2]);
                }
            __builtin_amdgcn_s_setprio(0);
            // p = 2^(s*C1 - C4) = e^(s/8 - 4);  |s/8| < 1*64/8 = 8 always.
            float rs = 0.f;
            uint32_t cw[2][4][2];
#pragma unroll
            for (int kb2 = 0; kb2 < 2; ++kb2)
#pragma unroll
                for (int a = 0; a < 4; ++a)
#pragma unroll
                    for (int p = 0; p < 2; ++p) {
                        float p0 = exp2fast(fmaf(acc_s[kb2][4 * a + 2 * p],     C1, -C4));
                        float p1 = exp2fast(fmaf(acc_s[kb2][4 * a + 2 * p + 1], C1, -C4));
                        rs += p0 + p1;
                        cw[kb2][a][p] = pk16(p0, p1);
                    }
            lrow[qs] += rs;
            __builtin_amdgcn_s_setprio(1);
#pragma unroll
            for (int ks = 0; ks < 4; ++ks) {
                int kb2 = ks >> 1, s = ks & 1;
                u32x2 r0 = __builtin_amdgcn_permlane32_swap(
                    cw[kb2][2 * s][0], cw[kb2][2 * s + 1][0], false, false);
                u32x2 r1 = __builtin_amdgcn_permlane32_swap(
                    cw[kb2][2 * s][1], cw[kb2][2 * s + 1][1], false, false);
                union { uint32_t u[4]; half8 h8; } pu;
                pu.u[0] = r0[0]; pu.u[1] = r1[0]; pu.u[2] = r0[1]; pu.u[3] = r1[1];
#pragma unroll
                for (int d2 = 0; d2 < 2; ++d2) {
                    int d = d2 * 32 + l31;
                    int uu = kt * 8 + ks * 2 + hi;
                    half8 vb = *(const half8*)(Vtp + d * 512 + ((uu ^ (d & 7)) << 3));
                    acc_o[qs][d2] = mfma32(pu.h8, vb, acc_o[qs][d2]);
                }
            }
            __builtin_amdgcn_s_setprio(0);
        }
    }
    // epilogue: lrow is split across hi halves -> combine, then divide.
#pragma unroll
    for (int qs = 0; qs < 2; ++qs) {
        lrow[qs] += __shfl_xor(lrow[qs], 32);
        size_t orow0 = (size_t)(b * NL + w8 * 64 + qs * 32);
#pragma unroll
        for (int c = 0; c < 4; ++c)
#pragma unroll
            for (int r = 0; r < 4; ++r) {
                int qrow = c * 8 + hi * 4 + r;
                float inv = 1.f / __shfl(lrow[qs], qrow);
#pragma unroll
                for (int d2 = 0; d2 < 2; ++d2)
                    attn_out[(orow0 + qrow) * NHD + h * ND + d2 * 32 + l31] =
                        (_Float16)(acc_o[qs][d2][c * 4 + r] * inv);
            }
    }
}

// ---------------- K2: output projection + f16 tanh residual ----------------
// tile 128e x 64m. BK=64, swizzled dbuf LDS, 2-phase pipeline.
// Grid: 512 = 8 XCD x (2 tn x 32 tm) -> attn B-panel fetched once per XCD.
__global__ __launch_bounds__(256) void final_gemm(
        const _Float16* __restrict__ woh, const _Float16* __restrict__ attn,
        const _Float16* __restrict__ xph, float* __restrict__ out) {
    __shared__ _Float16 Alds[2][128 * 64];
    __shared__ _Float16 Blds[2][64 * 64];
    int tid = threadIdx.x;
    int w = tid >> 6, l = tid & 63;
    int bid = blockIdx.x;
    int xcd = bid & 7, local = bid >> 3;   // 0..63
    int tn = local & 1;
    int tm = xcd * 32 + (local >> 1);
    int wn = w >> 1, wm = w & 1;
    int m16 = l & 15, g = l >> 4;
    int lrow8 = l >> 3;
    int kc16 = (l & 7) ^ lrow8;
    f32x4 acc[4][2] = {};

    const _Float16* Ag = woh + (size_t)tn * 128 * 512;
    const _Float16* Bg = attn + (size_t)tm * 64 * 512;

#define FIN_STAGE(kt, buf)                                                    \
    _Pragma("unroll") for (int i = 0; i < 4; ++i) {                           \
        int cA = w * 4 + i;                                                   \
        int row = cA * 8 + lrow8;                                             \
        cp16_g2l(Ag + (size_t)row * 512 + (kt) * 64 + kc16 * 8,               \
                 &Alds[buf][cA * 512]);                                       \
    }                                                                         \
    _Pragma("unroll") for (int i = 0; i < 2; ++i) {                           \
        int cB = w * 2 + i;                                                   \
        int row = cB * 8 + lrow8;                                             \
        cp16_g2l(Bg + (size_t)row * 512 + (kt) * 64 + kc16 * 8,               \
                 &Blds[buf][cB * 512]);                                       \
    }

    FIN_STAGE(0, 0);
    __syncthreads();
    int cur = 0;
    for (int kt = 0; kt < 8; ++kt) {
        if (kt < 7) { FIN_STAGE(kt + 1, cur ^ 1); }
#pragma unroll
        for (int ks = 0; ks < 2; ++ks) {
            half8 af[4], bf[2];
#pragma unroll
            for (int f = 0; f < 4; ++f) {
                int ra = wn * 64 + f * 16 + m16;
                af[f] = *(const half8*)(&Alds[cur][ra * 64 + (((ks * 4 + g) ^ (ra & 7)) << 3)]);
            }
#pragma unroll
            for (int f = 0; f < 2; ++f) {
                int rb = wm * 32 + f * 16 + m16;
                bf[f] = *(const half8*)(&Blds[cur][rb * 64 + (((ks * 4 + g) ^ (rb & 7)) << 3)]);
            }
#pragma unroll
            for (int nf = 0; nf < 4; ++nf)
#pragma unroll
                for (int mf = 0; mf < 2; ++mf)
                    acc[nf][mf] = mfma16(af[nf], bf[mf], acc[nf][mf]);
        }
        __syncthreads();
        cur ^= 1;
    }
#undef FIN_STAGE
#pragma unroll
    for (int nf = 0; nf < 4; ++nf) {
        int e = tn * 128 + wn * 64 + nf * 16 + g * 4;
#pragma unroll
        for (int mf = 0; mf < 2; ++mf) {
            int m = tm * 64 + wm * 32 + mf * 16 + m16;
            half4 hx = *(const half4*)(xph + (size_t)m * NE + e);
            f32x4 v = acc[nf][mf];
            float4 o;
            o.x = v[0] + fast_tanh((float)hx[0]);
            o.y = v[1] + fast_tanh((float)hx[1]);
            o.z = v[2] + fast_tanh((float)hx[2]);
            o.w = v[3] + fast_tanh((float)hx[3]);
            *(float4*)(out + (size_t)m * NE + e) = o;
        }
    }
}

extern "C" void kernel_launch(void* const* d_in, const int* in_sizes, int n_in,
                              void* d_out, int out_size, void* d_ws, size_t ws_size,
                              hipStream_t stream) {
    const float* x   = (const float*)d_in[0];
    const float* pos = (const float*)d_in[1];
    const float* Wq  = (const float*)d_in[2];
    const float* Wk  = (const float*)d_in[3];
    const float* Wv  = (const float*)d_in[4];
    const float* Wo  = (const float*)d_in[5];
    float* out = (float*)d_out;

    char* ws = (char*)d_ws;
    _Float16* xph   = (_Float16*)(ws);              //  8,388,608 B
    _Float16* wqkv  = (_Float16*)(ws + 8388608);    //    786,432 B
    _Float16* woh   = (_Float16*)(ws + 9175040);    //    262,144 B
    _Float16* attn  = (_Float16*)(ws + 9437184);    // 16,777,216 B

    prep<<<dim3(6144), dim3(256), 0, stream>>>(x, pos, Wq, Wk, Wv, Wo, wqkv, woh, xph);
    attn_fused<<<dim3(256), dim3(512), 0, stream>>>(wqkv, xph, attn);
    final_gemm<<<dim3(512), dim3(256), 0, stream>>>(woh, attn, xph, out);
}